// Round 14
// baseline (104.112 us; speedup 1.0000x reference)
//
#include <hip/hip_runtime.h>

#define N_NODES 50000
#define N_EDGES 800000
#define D 64
#define NCHUNK 64
#define CHUNK_E (N_EDGES / NCHUNK)   // 12500 edges per chunk
#define NRANGE 4
#define RANGE_N 16384                // nodes per range; packed u16 pairs in 32KB LDS
#define PAD 8                        // bucket padding -> unroll-8 pipelined gather
#define REC_CAP (N_EDGES + (PAD - 1) * N_NODES)   // 1,150,000 records max
#define NB_NODE 196                               // ceil(50001/256)
#define PLACE_BLOCKS (N_EDGES / 256)              // 3125

typedef int iv4 __attribute__((ext_vector_type(4)));

__device__ __forceinline__ unsigned short f2bf(float f) {   // RNE float->bf16
    unsigned int u = __float_as_uint(f);
    u += 0x7FFFu + ((u >> 16) & 1u);
    return (unsigned short)(u >> 16);
}
__device__ __forceinline__ float bf2f(unsigned int s) {     // low 16 bits -> float
    return __uint_as_float(s << 16);
}

// ---------- packed-u16 LDS histogram + local ranks ----------
__global__ __launch_bounds__(1024) void k_hist(const int* __restrict__ col,
                                               unsigned short* __restrict__ part,
                                               unsigned short* __restrict__ lrank) {
    __shared__ unsigned int h[RANGE_N / 2];   // 32 KiB
    int i = blockIdx.x >> 2;   // chunk 0..63
    int j = blockIdx.x & 3;    // range 0..3
    int t = threadIdx.x;
    for (int k = t; k < RANGE_N / 2; k += 1024) h[k] = 0;
    __syncthreads();
    int base = i * CHUNK_E;
    for (int e = base + t; e < base + CHUNK_E; e += 1024) {
        int c = col[e];
        if ((c >> 14) == j) {
            int local = c & (RANGE_N - 1);
            int sh = (local & 1) << 4;
            unsigned int lr = atomicAdd(&h[local >> 1], 1u << sh);
            lrank[e] = (unsigned short)((lr >> sh) & 0xffffu);
        }
    }
    __syncthreads();
    for (int k = t; k < RANGE_N; k += 1024) {
        int n = j * RANGE_N + k;
        if (n < N_NODES)
            part[(size_t)i * N_NODES + n] =
                (unsigned short)((h[k >> 1] >> ((k & 1) << 4)) & 0xffffu);
    }
}

// ---------- per-node chunk scan + block-local node scan ----------
__global__ __launch_bounds__(256) void k_scan(unsigned short* __restrict__ part,
                                              int* __restrict__ start,
                                              int* __restrict__ cnttot,
                                              int* __restrict__ partials) {
    __shared__ int s[256];
    int b = blockIdx.x, t = threadIdx.x;
    int n = b * 256 + t;
    unsigned int run = 0;
    if (n < N_NODES) {
#pragma unroll 8
        for (int i = 0; i < NCHUNK; ++i) {
            size_t idx = (size_t)i * N_NODES + n;
            unsigned int v = part[idx];
            part[idx] = (unsigned short)run;
            run += v;
        }
        cnttot[n] = (int)run;   // unpadded count (for pad-fill)
    }
    int cnt = (n < N_NODES) ? (int)((run + PAD - 1) & ~(unsigned)(PAD - 1)) : 0;
    s[t] = cnt;
    __syncthreads();
    for (int off = 1; off < 256; off <<= 1) {
        int a = (t >= off) ? s[t - off] : 0;
        __syncthreads();
        s[t] += a;
        __syncthreads();
    }
    if (n <= N_NODES) start[n] = s[t] - cnt;   // block-local exclusive prefix
    if (t == 255) partials[b] = s[255];
}

// ---------- finalize start ----------
__global__ __launch_bounds__(256) void k_scanfin(int* __restrict__ start,
                                                 const int* __restrict__ partials) {
    __shared__ int red[256];
    int b = blockIdx.x, t = threadIdx.x;
    red[t] = (t < b) ? partials[t] : 0;   // b <= 195 < 256
    __syncthreads();
    for (int off = 128; off > 0; off >>= 1) {
        if (t < off) red[t] += red[t + off];
        __syncthreads();
    }
    int offset = red[0];
    int n = b * 256 + t;
    if (n <= N_NODES) start[n] += offset;
}

// ---------- place 4-byte records (u16 src | bf16 ew) + pad-fill tails ----------
__global__ __launch_bounds__(256) void k_place(const int* __restrict__ ei,
                                               const float* __restrict__ ew,
                                               const int* __restrict__ start,
                                               const int* __restrict__ cnttot,
                                               const unsigned short* __restrict__ part,
                                               const unsigned short* __restrict__ lrank,
                                               unsigned int* __restrict__ rec) {
    int b = blockIdx.x, t = threadIdx.x;
    if (b < PLACE_BLOCKS) {
        int e = b * 256 + t;
        int c = ei[N_EDGES + e];
        int i = e / CHUNK_E;   // compile-time magic-div
        int pos = start[c] + (int)part[(size_t)i * N_NODES + c] + (int)lrank[e];
        rec[pos] = (unsigned int)ei[e] | ((unsigned int)f2bf(ew[e]) << 16);
    } else {
        int n = (b - PLACE_BLOCKS) * 256 + t;
        if (n < N_NODES) {
            int j = start[n] + cnttot[n];
            int j1 = start[n + 1];
            for (; j < j1; ++j) rec[j] = 0u;   // (src=0, w=0.0f)
        }
    }
}

// ---------- deg from CSR, wave-parallel ----------
__global__ __launch_bounds__(256) void k_deg(const int* __restrict__ start,
                                             const unsigned int* __restrict__ rec,
                                             float* __restrict__ dis) {
    int wave = threadIdx.x >> 6;
    int lane = threadIdx.x & 63;
    int n = blockIdx.x * 4 + wave;   // 12500 * 4 = 50000 exact
    int j0 = start[n], j1 = start[n + 1];
    float s = 0.0f;
    for (int j = j0 + lane; j < j1; j += 64) s += bf2f(rec[j] >> 16);  // pads add 0
    for (int off = 32; off > 0; off >>= 1) s += __shfl_down(s, off);
    if (lane == 0) dis[n] = rsqrtf(1.0f + s);   // self-loop weight 1
}

// ---------- xw16 = bf16( dis[row] * (x @ W) ), 64 rows/block for load balance ----------
__global__ __launch_bounds__(256) void k_xw(const float* __restrict__ x,
                                            const float* __restrict__ W,
                                            const float* __restrict__ dis,
                                            unsigned short* __restrict__ xw16) {
    __shared__ float Ws[64 * 64];    // 16 KiB
    __shared__ float xs[64 * 68];    // 17 KiB (pad 68)
    int t = threadIdx.x;
    int r0 = blockIdx.x * 64;

    for (int i = t; i < 1024; i += 256)
        ((float4*)Ws)[i] = ((const float4*)W)[i];
    for (int i = t; i < 1024; i += 256) {
        int row = i >> 4, k4 = i & 15;
        int gr = r0 + row;
        float4 v = make_float4(0.f, 0.f, 0.f, 0.f);
        if (gr < N_NODES) v = ((const float4*)x)[gr * 16 + k4];
        *(float4*)&xs[row * 68 + k4 * 4] = v;
    }
    __syncthreads();

    int cg = t & 15;
    int rg = t >> 4;
    float4 acc[4];
#pragma unroll
    for (int i = 0; i < 4; ++i) acc[i] = make_float4(0.f, 0.f, 0.f, 0.f);

    for (int k4 = 0; k4 < 16; ++k4) {
        float4 xv[4];
#pragma unroll
        for (int i = 0; i < 4; ++i)
            xv[i] = *(const float4*)&xs[(rg + 16 * i) * 68 + k4 * 4];
        float4 w0 = *(const float4*)&Ws[(k4 * 4 + 0) * 64 + cg * 4];
        float4 w1 = *(const float4*)&Ws[(k4 * 4 + 1) * 64 + cg * 4];
        float4 w2 = *(const float4*)&Ws[(k4 * 4 + 2) * 64 + cg * 4];
        float4 w3 = *(const float4*)&Ws[(k4 * 4 + 3) * 64 + cg * 4];
#pragma unroll
        for (int i = 0; i < 4; ++i) {
            acc[i].x = fmaf(xv[i].x, w0.x, acc[i].x); acc[i].y = fmaf(xv[i].x, w0.y, acc[i].y);
            acc[i].z = fmaf(xv[i].x, w0.z, acc[i].z); acc[i].w = fmaf(xv[i].x, w0.w, acc[i].w);
            acc[i].x = fmaf(xv[i].y, w1.x, acc[i].x); acc[i].y = fmaf(xv[i].y, w1.y, acc[i].y);
            acc[i].z = fmaf(xv[i].y, w1.z, acc[i].z); acc[i].w = fmaf(xv[i].y, w1.w, acc[i].w);
            acc[i].x = fmaf(xv[i].z, w2.x, acc[i].x); acc[i].y = fmaf(xv[i].z, w2.y, acc[i].y);
            acc[i].z = fmaf(xv[i].z, w2.z, acc[i].z); acc[i].w = fmaf(xv[i].z, w2.w, acc[i].w);
            acc[i].x = fmaf(xv[i].w, w3.x, acc[i].x); acc[i].y = fmaf(xv[i].w, w3.y, acc[i].y);
            acc[i].z = fmaf(xv[i].w, w3.z, acc[i].z); acc[i].w = fmaf(xv[i].w, w3.w, acc[i].w);
        }
    }

#pragma unroll
    for (int i = 0; i < 4; ++i) {
        int row = r0 + rg + 16 * i;
        if (row < N_NODES) {
            float s = dis[row];
            ushort4 s4 = make_ushort4(f2bf(acc[i].x * s), f2bf(acc[i].y * s),
                                      f2bf(acc[i].z * s), f2bf(acc[i].w * s));
            *(ushort4*)&xw16[row * 64 + cg * 4] = s4;
        }
    }
}

// ---------- gather: one wave per node, unroll-8 x 2-stage pipeline, 4B records ----------
__global__ __launch_bounds__(256) void k_gather(const int* __restrict__ start,
                                                const unsigned int* __restrict__ rec,
                                                const unsigned short* __restrict__ xw16,
                                                const float* __restrict__ dis,
                                                const float* __restrict__ bias,
                                                float* __restrict__ out) {
    int wave = threadIdx.x >> 6;
    int c = threadIdx.x & 63;
    int n = blockIdx.x * 4 + wave;   // 12500 * 4 = 50000 exact
    float di = dis[n];
    float acc[8];
#pragma unroll
    for (int k = 0; k < 8; ++k) acc[k] = 0.f;
    acc[0] = bf2f((unsigned int)xw16[n * 64 + c]);   // self-loop (xw pre-scaled by dis)
    int j0 = start[n], j1 = start[n + 1];    // multiples of 8 -> 32B aligned
    int iters = (j1 - j0) >> 3;
    const iv4* rq = (const iv4*)(rec + j0);
    iv4 q0 = rq[0], q1 = rq[1];              // over-read safe: ws slack beyond rec
    for (int it = 0; it < iters; ++it) {
        iv4 p0 = q0, p1 = q1;
        q0 = rq[2 * it + 2];                 // prefetch next 8 records (over-read safe)
        q1 = rq[2 * it + 3];
        unsigned int r[8] = { (unsigned int)p0.x, (unsigned int)p0.y,
                              (unsigned int)p0.z, (unsigned int)p0.w,
                              (unsigned int)p1.x, (unsigned int)p1.y,
                              (unsigned int)p1.z, (unsigned int)p1.w };
        float v[8];
#pragma unroll
        for (int k = 0; k < 8; ++k)
            v[k] = bf2f((unsigned int)xw16[(r[k] & 0xffffu) * 64 + c]);
#pragma unroll
        for (int k = 0; k < 8; ++k)
            acc[k] = fmaf(v[k], bf2f(r[k] >> 16), acc[k]);
    }
    float a = ((acc[0] + acc[1]) + (acc[2] + acc[3])) + ((acc[4] + acc[5]) + (acc[6] + acc[7]));
    out[n * 64 + c] = fmaf(a, di, bias[c]);
}

extern "C" void kernel_launch(void* const* d_in, const int* in_sizes, int n_in,
                              void* d_out, int out_size, void* d_ws, size_t ws_size,
                              hipStream_t stream) {
    const float* x    = (const float*)d_in[0];
    const float* W    = (const float*)d_in[1];
    const float* bias = (const float*)d_in[2];
    const float* ew   = (const float*)d_in[3];
    const int*   ei   = (const int*)d_in[4];   // (2,E) flat: [0:E) src, [E:2E) dst
    float* out = (float*)d_out;

    // ---- workspace layout (bytes) ----
    char* wsb = (char*)d_ws;
    unsigned int*   rec   = (unsigned int*)wsb;                 //  6,200,000 B (4.6 MB used + slack)
    unsigned short* xw16  = (unsigned short*)(wsb + 6200000);   //  6,400,000 B
    unsigned short* lrank = (unsigned short*)(wsb + 12600000);  //  1,600,000 B
    unsigned short* part  = (unsigned short*)(wsb + 14200000);  //  6,400,000 B
    float*          dis   = (float*)(wsb + 20600000);           //    200,000 B
    int*            cnttot= (int*)(wsb + 20800000);             //    200,000 B
    int*            start = (int*)(wsb + 21000000);             //    200,004 B
    int*            partials = (int*)(wsb + 21200016);          //        784 B

    k_hist<<<NCHUNK * NRANGE, 1024, 0, stream>>>(ei + N_EDGES, part, lrank);
    k_scan<<<NB_NODE, 256, 0, stream>>>(part, start, cnttot, partials);
    k_scanfin<<<NB_NODE, 256, 0, stream>>>(start, partials);
    k_place<<<PLACE_BLOCKS + NB_NODE, 256, 0, stream>>>(ei, ew, start, cnttot, part, lrank, rec);
    k_deg<<<N_NODES / 4, 256, 0, stream>>>(start, rec, dis);
    k_xw<<<(N_NODES + 63) / 64, 256, 0, stream>>>(x, W, dis, xw16);
    k_gather<<<N_NODES / 4, 256, 0, stream>>>(start, rec, xw16, dis, bias, out);
}

// Round 15
// 87.711 us; speedup vs baseline: 1.1870x; 1.1870x over previous
//
#include <hip/hip_runtime.h>

#define N_NODES 50000
#define N_EDGES 800000
#define D 64
#define NCHUNK 64
#define CHUNK_E (N_EDGES / NCHUNK)   // 12500 edges per chunk
#define NRANGE 4
#define RANGE_N 16384                // nodes per range; packed u16 pairs in 32KB LDS
#define PAD 8                        // bucket padding -> unroll-8 pipelined gather
#define REC_CAP (N_EDGES + (PAD - 1) * N_NODES)   // 1,150,000 records max
#define NB_NODE 196                               // ceil(50001/256)
#define PLACE_BLOCKS (N_EDGES / 256)              // 3125

typedef int iv4 __attribute__((ext_vector_type(4)));

__device__ __forceinline__ unsigned short f2bf(float f) {   // RNE float->bf16
    unsigned int u = __float_as_uint(f);
    u += 0x7FFFu + ((u >> 16) & 1u);
    return (unsigned short)(u >> 16);
}
__device__ __forceinline__ float bf2f(unsigned int s) {     // low 16 bits -> float
    return __uint_as_float(s << 16);
}

// ---------- packed-u16 LDS histogram + local ranks ----------
__global__ __launch_bounds__(1024) void k_hist(const int* __restrict__ col,
                                               unsigned short* __restrict__ part,
                                               unsigned short* __restrict__ lrank) {
    __shared__ unsigned int h[RANGE_N / 2];   // 32 KiB
    int i = blockIdx.x >> 2;   // chunk 0..63
    int j = blockIdx.x & 3;    // range 0..3
    int t = threadIdx.x;
    for (int k = t; k < RANGE_N / 2; k += 1024) h[k] = 0;
    __syncthreads();
    int base = i * CHUNK_E;
    for (int e = base + t; e < base + CHUNK_E; e += 1024) {
        int c = col[e];
        if ((c >> 14) == j) {
            int local = c & (RANGE_N - 1);
            int sh = (local & 1) << 4;
            unsigned int lr = atomicAdd(&h[local >> 1], 1u << sh);
            lrank[e] = (unsigned short)((lr >> sh) & 0xffffu);
        }
    }
    __syncthreads();
    for (int k = t; k < RANGE_N; k += 1024) {
        int n = j * RANGE_N + k;
        if (n < N_NODES)
            part[(size_t)i * N_NODES + n] =
                (unsigned short)((h[k >> 1] >> ((k & 1) << 4)) & 0xffffu);
    }
}

// ---------- per-node chunk scan + block-local node scan ----------
__global__ __launch_bounds__(256) void k_scan(unsigned short* __restrict__ part,
                                              int* __restrict__ start,
                                              int* __restrict__ cnttot,
                                              int* __restrict__ partials) {
    __shared__ int s[256];
    int b = blockIdx.x, t = threadIdx.x;
    int n = b * 256 + t;
    unsigned int run = 0;
    if (n < N_NODES) {
#pragma unroll 8
        for (int i = 0; i < NCHUNK; ++i) {
            size_t idx = (size_t)i * N_NODES + n;
            unsigned int v = part[idx];
            part[idx] = (unsigned short)run;
            run += v;
        }
        cnttot[n] = (int)run;   // unpadded count (for pad-fill)
    }
    int cnt = (n < N_NODES) ? (int)((run + PAD - 1) & ~(unsigned)(PAD - 1)) : 0;
    s[t] = cnt;
    __syncthreads();
    for (int off = 1; off < 256; off <<= 1) {
        int a = (t >= off) ? s[t - off] : 0;
        __syncthreads();
        s[t] += a;
        __syncthreads();
    }
    if (n <= N_NODES) start[n] = s[t] - cnt;   // block-local exclusive prefix
    if (t == 255) partials[b] = s[255];
}

// ---------- finalize start ----------
__global__ __launch_bounds__(256) void k_scanfin(int* __restrict__ start,
                                                 const int* __restrict__ partials) {
    __shared__ int red[256];
    int b = blockIdx.x, t = threadIdx.x;
    red[t] = (t < b) ? partials[t] : 0;   // b <= 195 < 256
    __syncthreads();
    for (int off = 128; off > 0; off >>= 1) {
        if (t < off) red[t] += red[t + off];
        __syncthreads();
    }
    int offset = red[0];
    int n = b * 256 + t;
    if (n <= N_NODES) start[n] += offset;
}

// ---------- place 4-byte records (u16 src | bf16 ew) + pad-fill tails ----------
__global__ __launch_bounds__(256) void k_place(const int* __restrict__ ei,
                                               const float* __restrict__ ew,
                                               const int* __restrict__ start,
                                               const int* __restrict__ cnttot,
                                               const unsigned short* __restrict__ part,
                                               const unsigned short* __restrict__ lrank,
                                               unsigned int* __restrict__ rec) {
    int b = blockIdx.x, t = threadIdx.x;
    if (b < PLACE_BLOCKS) {
        int e = b * 256 + t;
        int c = ei[N_EDGES + e];
        int i = e / CHUNK_E;   // compile-time magic-div
        int pos = start[c] + (int)part[(size_t)i * N_NODES + c] + (int)lrank[e];
        rec[pos] = (unsigned int)ei[e] | ((unsigned int)f2bf(ew[e]) << 16);
    } else {
        int n = (b - PLACE_BLOCKS) * 256 + t;
        if (n < N_NODES) {
            int j = start[n] + cnttot[n];
            int j1 = start[n + 1];
            for (; j < j1; ++j) rec[j] = 0u;   // (src=0, w=0.0f)
        }
    }
}

// ---------- deg from CSR, wave-parallel ----------
__global__ __launch_bounds__(256) void k_deg(const int* __restrict__ start,
                                             const unsigned int* __restrict__ rec,
                                             float* __restrict__ dis) {
    int wave = threadIdx.x >> 6;
    int lane = threadIdx.x & 63;
    int n = blockIdx.x * 4 + wave;   // 12500 * 4 = 50000 exact
    int j0 = start[n], j1 = start[n + 1];
    float s = 0.0f;
    for (int j = j0 + lane; j < j1; j += 64) s += bf2f(rec[j] >> 16);  // pads add 0
    for (int off = 32; off > 0; off >>= 1) s += __shfl_down(s, off);
    if (lane == 0) dis[n] = rsqrtf(1.0f + s);   // self-loop weight 1
}

// ---------- xw16 = bf16( dis[row] * (x @ W) ), register-lean ----------
// launch_bounds(256,4) caps VGPR at 128; unroll-2 keeps live ranges small.
__global__ __launch_bounds__(256, 4) void k_xw(const float* __restrict__ x,
                                               const float* __restrict__ W,
                                               const float* __restrict__ dis,
                                               unsigned short* __restrict__ xw16) {
    __shared__ float Ws[64 * 64];    // 16 KiB
    __shared__ float xs[64 * 68];    // 17 KiB (pad 68)
    int t = threadIdx.x;
    int r0 = blockIdx.x * 64;

    for (int i = t; i < 1024; i += 256)
        ((float4*)Ws)[i] = ((const float4*)W)[i];
    for (int i = t; i < 1024; i += 256) {
        int row = i >> 4, k4 = i & 15;
        int gr = r0 + row;
        float4 v = make_float4(0.f, 0.f, 0.f, 0.f);
        if (gr < N_NODES) v = ((const float4*)x)[gr * 16 + k4];
        *(float4*)&xs[row * 68 + k4 * 4] = v;
    }
    __syncthreads();

    int cg = t & 15;
    int rg = t >> 4;
    float4 acc[4];
#pragma unroll
    for (int i = 0; i < 4; ++i) acc[i] = make_float4(0.f, 0.f, 0.f, 0.f);

#pragma unroll 2
    for (int k4 = 0; k4 < 16; ++k4) {
        float4 xv[4];
#pragma unroll
        for (int i = 0; i < 4; ++i)
            xv[i] = *(const float4*)&xs[(rg + 16 * i) * 68 + k4 * 4];
        float4 w0 = *(const float4*)&Ws[(k4 * 4 + 0) * 64 + cg * 4];
        float4 w1 = *(const float4*)&Ws[(k4 * 4 + 1) * 64 + cg * 4];
        float4 w2 = *(const float4*)&Ws[(k4 * 4 + 2) * 64 + cg * 4];
        float4 w3 = *(const float4*)&Ws[(k4 * 4 + 3) * 64 + cg * 4];
#pragma unroll
        for (int i = 0; i < 4; ++i) {
            acc[i].x = fmaf(xv[i].x, w0.x, acc[i].x); acc[i].y = fmaf(xv[i].x, w0.y, acc[i].y);
            acc[i].z = fmaf(xv[i].x, w0.z, acc[i].z); acc[i].w = fmaf(xv[i].x, w0.w, acc[i].w);
            acc[i].x = fmaf(xv[i].y, w1.x, acc[i].x); acc[i].y = fmaf(xv[i].y, w1.y, acc[i].y);
            acc[i].z = fmaf(xv[i].y, w1.z, acc[i].z); acc[i].w = fmaf(xv[i].y, w1.w, acc[i].w);
            acc[i].x = fmaf(xv[i].z, w2.x, acc[i].x); acc[i].y = fmaf(xv[i].z, w2.y, acc[i].y);
            acc[i].z = fmaf(xv[i].z, w2.z, acc[i].z); acc[i].w = fmaf(xv[i].z, w2.w, acc[i].w);
            acc[i].x = fmaf(xv[i].w, w3.x, acc[i].x); acc[i].y = fmaf(xv[i].w, w3.y, acc[i].y);
            acc[i].z = fmaf(xv[i].w, w3.z, acc[i].z); acc[i].w = fmaf(xv[i].w, w3.w, acc[i].w);
        }
    }

#pragma unroll
    for (int i = 0; i < 4; ++i) {
        int row = r0 + rg + 16 * i;
        if (row < N_NODES) {
            float s = dis[row];
            ushort4 s4 = make_ushort4(f2bf(acc[i].x * s), f2bf(acc[i].y * s),
                                      f2bf(acc[i].z * s), f2bf(acc[i].w * s));
            *(ushort4*)&xw16[row * 64 + cg * 4] = s4;
        }
    }
}

// ---------- gather: one wave per node, unroll-8 x 2-stage pipeline, 4B records ----------
__global__ __launch_bounds__(256) void k_gather(const int* __restrict__ start,
                                                const unsigned int* __restrict__ rec,
                                                const unsigned short* __restrict__ xw16,
                                                const float* __restrict__ dis,
                                                const float* __restrict__ bias,
                                                float* __restrict__ out) {
    int wave = threadIdx.x >> 6;
    int c = threadIdx.x & 63;
    int n = blockIdx.x * 4 + wave;   // 12500 * 4 = 50000 exact
    float di = dis[n];
    float acc[8];
#pragma unroll
    for (int k = 0; k < 8; ++k) acc[k] = 0.f;
    acc[0] = bf2f((unsigned int)xw16[n * 64 + c]);   // self-loop (xw pre-scaled by dis)
    int j0 = start[n], j1 = start[n + 1];    // multiples of 8 -> 32B aligned
    int iters = (j1 - j0) >> 3;
    const iv4* rq = (const iv4*)(rec + j0);
    iv4 q0 = rq[0], q1 = rq[1];              // over-read safe: ws slack beyond rec
    for (int it = 0; it < iters; ++it) {
        iv4 p0 = q0, p1 = q1;
        q0 = rq[2 * it + 2];                 // prefetch next 8 records (over-read safe)
        q1 = rq[2 * it + 3];
        unsigned int r[8] = { (unsigned int)p0.x, (unsigned int)p0.y,
                              (unsigned int)p0.z, (unsigned int)p0.w,
                              (unsigned int)p1.x, (unsigned int)p1.y,
                              (unsigned int)p1.z, (unsigned int)p1.w };
        float v[8];
#pragma unroll
        for (int k = 0; k < 8; ++k)
            v[k] = bf2f((unsigned int)xw16[(r[k] & 0xffffu) * 64 + c]);
#pragma unroll
        for (int k = 0; k < 8; ++k)
            acc[k] = fmaf(v[k], bf2f(r[k] >> 16), acc[k]);
    }
    float a = ((acc[0] + acc[1]) + (acc[2] + acc[3])) + ((acc[4] + acc[5]) + (acc[6] + acc[7]));
    out[n * 64 + c] = fmaf(a, di, bias[c]);
}

extern "C" void kernel_launch(void* const* d_in, const int* in_sizes, int n_in,
                              void* d_out, int out_size, void* d_ws, size_t ws_size,
                              hipStream_t stream) {
    const float* x    = (const float*)d_in[0];
    const float* W    = (const float*)d_in[1];
    const float* bias = (const float*)d_in[2];
    const float* ew   = (const float*)d_in[3];
    const int*   ei   = (const int*)d_in[4];   // (2,E) flat: [0:E) src, [E:2E) dst
    float* out = (float*)d_out;

    // ---- workspace layout (bytes) ----
    char* wsb = (char*)d_ws;
    unsigned int*   rec   = (unsigned int*)wsb;                 //  6,200,000 B (4.6 MB used + slack)
    unsigned short* xw16  = (unsigned short*)(wsb + 6200000);   //  6,400,000 B
    unsigned short* lrank = (unsigned short*)(wsb + 12600000);  //  1,600,000 B
    unsigned short* part  = (unsigned short*)(wsb + 14200000);  //  6,400,000 B
    float*          dis   = (float*)(wsb + 20600000);           //    200,000 B
    int*            cnttot= (int*)(wsb + 20800000);             //    200,000 B
    int*            start = (int*)(wsb + 21000000);             //    200,004 B
    int*            partials = (int*)(wsb + 21200016);          //        784 B

    k_hist<<<NCHUNK * NRANGE, 1024, 0, stream>>>(ei + N_EDGES, part, lrank);
    k_scan<<<NB_NODE, 256, 0, stream>>>(part, start, cnttot, partials);
    k_scanfin<<<NB_NODE, 256, 0, stream>>>(start, partials);
    k_place<<<PLACE_BLOCKS + NB_NODE, 256, 0, stream>>>(ei, ew, start, cnttot, part, lrank, rec);
    k_deg<<<N_NODES / 4, 256, 0, stream>>>(start, rec, dis);
    k_xw<<<(N_NODES + 63) / 64, 256, 0, stream>>>(x, W, dis, xw16);
    k_gather<<<N_NODES / 4, 256, 0, stream>>>(start, rec, xw16, dis, bias, out);
}